// Round 1
// baseline (172.054 us; speedup 1.0000x reference)
//
#include <hip/hip_runtime.h>
#include <math.h>

// Problem constants (from reference)
#define Gc 36
#define Ac 5
#define Bc 32
#define Tc 8
#define NCELLS (Bc*Gc*Gc*Ac)   // 207360
#define NT 256                  // threads per block (both kernels)
#define NBLK1 256               // blocks for conf^2 partial kernel

// ---------------------------------------------------------------------------
// Kernel 1: partial sums of conf^2 over all N cells (conf = bbox_pred[...,4])
// ---------------------------------------------------------------------------
__global__ void conf_sq_partial(const float* __restrict__ bbox_pred,
                                float* __restrict__ partial) {
    __shared__ float red[NT];
    float acc = 0.0f;
    for (int idx = blockIdx.x * blockDim.x + threadIdx.x; idx < NCELLS;
         idx += gridDim.x * blockDim.x) {
        float c = bbox_pred[(size_t)idx * 5 + 4];
        acc += c * c;
    }
    red[threadIdx.x] = acc;
    __syncthreads();
    for (int s = NT / 2; s > 0; s >>= 1) {
        if (threadIdx.x < s) red[threadIdx.x] += red[threadIdx.x + s];
        __syncthreads();
    }
    if (threadIdx.x == 0) partial[blockIdx.x] = red[0];
}

// ---------------------------------------------------------------------------
// Kernel 2: everything else (256 targets), one block of 256 threads
// ---------------------------------------------------------------------------
__device__ __forceinline__ float block_sum(float v, float* red, int tid) {
    red[tid] = v;
    __syncthreads();
    for (int s = NT / 2; s > 0; s >>= 1) {
        if (tid < s) red[tid] += red[tid + s];
        __syncthreads();
    }
    float r = red[0];
    __syncthreads();
    return r;
}

__global__ void finalize(const float* __restrict__ bbox_pred,
                         const float* __restrict__ lm_pred,
                         const float* __restrict__ bbox_tgt,
                         const float* __restrict__ lm_tgt,
                         const float* __restrict__ partial,
                         float* __restrict__ out) {
    const int tid = threadIdx.x;            // 0..255
    const int b = tid >> 3;                  // batch
    const int t = tid & 7;                   // target idx

    __shared__ int   s_lin[NT];
    __shared__ float s_red[NT];
    __shared__ int   s_cnt[NT];

    // ---- load target, compute cell + anchor argmax ----
    const float* tg = bbox_tgt + (size_t)(b * Tc + t) * 4;
    float x = tg[0], y = tg[1], w = tg[2], h = tg[3];
    bool valid = ((x + y + w + h) != 0.0f);

    float gx = x * (float)Gc, gy = y * (float)Gc;
    int gi = (int)floorf(gx);
    int gj = (int)floorf(gy);
    float fx = gx - (float)gi;
    float fy = gy - (float)gj;

    // gt anchor box corners (IoU uses the +1 convention)
    float x1a = fx - w * 0.5f, x2a = fx + w * 0.5f;
    float y1a = fy - h * 0.5f, y2a = fy + h * 0.5f;
    float a1 = (x2a - x1a + 1.0f) * (y2a - y1a + 1.0f);

    const float adim[Ac] = {0.24f, 0.12f, 0.08f, 0.28f, 0.15f};
    int best_a = 0;
    float best_iou = -1e30f;
    for (int a = 0; a < Ac; ++a) {
        float x1b = 0.5f - adim[a] * 0.5f, x2b = 0.5f + adim[a] * 0.5f;
        float y1b = x1b, y2b = x2b;  // square anchors, cy=cx=0.5
        float iw = fminf(x2a, x2b) - fmaxf(x1a, x1b) + 1.0f;
        float ih = fminf(y2a, y2b) - fmaxf(y1a, y1b) + 1.0f;
        float inter = iw * ih;
        float a2 = (x2b - x1b + 1.0f) * (y2b - y1b + 1.0f);
        float iou = inter / (a1 + a2 - inter + 1e-16f);
        if (iou > best_iou) { best_iou = iou; best_a = a; }  // first-max tie-break
    }

    float l0 = log1pf(fx), l1 = log1pf(fy), l2 = log1pf(w), l3 = log1pf(h);

    int lin = valid ? (((b * Gc + gj) * Gc + gi) * Ac + best_a) : NCELLS;
    s_lin[tid] = lin;
    __syncthreads();

    // ---- winner: valid and no larger-t target in same batch with same lin ----
    bool winner = valid;
    if (valid) {
        for (int t2 = t + 1; t2 < Tc; ++t2) {
            if (s_lin[(b << 3) + t2] == lin) { winner = false; break; }
        }
    }

    // ---- per-winner contributions ----
    float c_nme = 0.0f, c_sl1 = 0.0f, c_cobj = 0.0f, c_csq = 0.0f;
    int c_cnt = 0;
    if (winner) {
        c_cnt = 1;
        const float* bp = bbox_pred + (size_t)lin * 5;
        float conf = bp[4];
        c_cobj = (conf - 1.0f) * (conf - 1.0f);
        c_csq  = conf * conf;
        float lb[4] = {l0, l1, l2, l3};
        for (int k = 0; k < 4; ++k) {
            float d = bp[k] - lb[k];
            float ad = fabsf(d);
            c_sl1 += (ad < 1.0f) ? 0.5f * d * d : (ad - 0.5f);
        }
        const float* lp = lm_pred + (size_t)lin * 136;
        const float* lt = lm_tgt + (size_t)(b * Tc + t) * 136;
        float acc = 0.0f;
        for (int j = 0; j < 136; ++j) {
            float d = lp[j] - lt[j];
            acc += d * d;
        }
        float dist = sqrtf(acc);
        float wh = l2 * l3;                       // gt_boxes[...,2]*gt_boxes[...,3]
        c_nme = dist / (sqrtf(wh) * 288.0f * 68.0f);   // /nobj applied after count
    }

    // ---- reductions ----
    s_cnt[tid] = c_cnt;
    __syncthreads();
    for (int s = NT / 2; s > 0; s >>= 1) {
        if (tid < s) s_cnt[tid] += s_cnt[tid + s];
        __syncthreads();
    }
    int cnt = s_cnt[0];
    __syncthreads();

    float nobj    = fmaxf((float)cnt, 1.0f);
    float n_noobj = fmaxf((float)(NCELLS - cnt), 1.0f);

    float sum_nme  = block_sum(c_nme,  s_red, tid);
    float sum_sl1  = block_sum(c_sl1,  s_red, tid);
    float sum_cobj = block_sum(c_cobj, s_red, tid);
    float sum_csq  = block_sum(c_csq,  s_red, tid);
    float s_total  = block_sum(partial[tid], s_red, tid);  // NBLK1 == NT

    if (tid == 0) {
        out[0] = sum_nme / nobj;                                   // nme
        out[1] = 5.0f * sum_sl1 / (nobj * 4.0f);                   // loc_loss
        out[2] = 0.5f * (s_total - sum_csq) / n_noobj              // conf_loss
               + sum_cobj / nobj;
    }

    // ---- best_pred: per-(b,t) gather of cell predictions, IoU argmax ----
    const float* cp = bbox_pred + (size_t)((b * Gc + gj) * Gc + gi) * Ac * 5;
    float x1g = l0 - l2 * 0.5f, x2g = l0 + l2 * 0.5f;
    float y1g = l1 - l3 * 0.5f, y2g = l1 + l3 * 0.5f;
    float ag = (x2g - x1g + 1.0f) * (y2g - y1g + 1.0f);
    int bp_idx = 0;
    float bp_iou = -1e30f;
    for (int a = 0; a < Ac; ++a) {
        float cx = cp[a * 5 + 0], cy = cp[a * 5 + 1];
        float pw = cp[a * 5 + 2], ph = cp[a * 5 + 3];
        float x1p = cx - pw * 0.5f, x2p = cx + pw * 0.5f;
        float y1p = cy - ph * 0.5f, y2p = cy + ph * 0.5f;
        float iw = fminf(x2g, x2p) - fmaxf(x1g, x1p) + 1.0f;
        float ih = fminf(y2g, y2p) - fmaxf(y1g, y1p) + 1.0f;
        float inter = iw * ih;
        float ap = (x2p - x1p + 1.0f) * (y2p - y1p + 1.0f);
        float iou = inter / (ag + ap - inter + 1e-16f);
        if (iou > bp_iou) { bp_iou = iou; bp_idx = a; }  // first-max tie-break
    }
    float bx = cp[bp_idx * 5 + 0], by = cp[bp_idx * 5 + 1];
    float bw = cp[bp_idx * 5 + 2], bh = cp[bp_idx * 5 + 3];
    float bconf = cp[bp_idx * 5 + 4];
    float o0 = bx - bw * 0.5f, o1 = bx + bw * 0.5f;
    float o2 = by - bh * 0.5f, o3 = by + bh * 0.5f;

    float* op = out + 3 + (size_t)tid * 5;
    if (valid) {
        op[0] = o0; op[1] = o1; op[2] = o2; op[3] = o3; op[4] = bconf;
    } else {
        op[0] = 0.0f; op[1] = 0.0f; op[2] = 0.0f; op[3] = 0.0f; op[4] = 0.0f;
    }
}

extern "C" void kernel_launch(void* const* d_in, const int* in_sizes, int n_in,
                              void* d_out, int out_size, void* d_ws, size_t ws_size,
                              hipStream_t stream) {
    const float* bbox_pred = (const float*)d_in[0];   // (32,36,36,5,5)
    const float* lm_pred   = (const float*)d_in[1];   // (32,36,36,5,68,2)
    const float* bbox_tgt  = (const float*)d_in[2];   // (32,8,4)
    const float* lm_tgt    = (const float*)d_in[3];   // (32,8,68,2)
    float* out = (float*)d_out;                       // [nme, loc, conf, best_pred(1280)]
    float* partial = (float*)d_ws;                    // NBLK1 floats

    conf_sq_partial<<<NBLK1, NT, 0, stream>>>(bbox_pred, partial);
    finalize<<<1, NT, 0, stream>>>(bbox_pred, lm_pred, bbox_tgt, lm_tgt,
                                   partial, out);
}

// Round 2
// 159.040 us; speedup vs baseline: 1.0818x; 1.0818x over previous
//
#include <hip/hip_runtime.h>
#include <math.h>

// Problem constants (from reference)
#define Gc 36
#define Ac 5
#define Bc 32
#define Tc 8
#define NCELLS (Bc*Gc*Gc*Ac)     // 207360
#define NFLOATS (NCELLS*5)       // 1036800
#define NF4 (NFLOATS/4)          // 259200
#define NT 256
#define CONF_BLOCKS 128

// ws layout (floats / ints):
//   ws_f[0..127]          conf^2 partials (CONF_BLOCKS)
//   ws_i[256..511]        lin per target
//   ws_i[512..767]        winner flag per target
//   ws_f[1024..1279]      landmark dist per target (0 for non-winner)

__device__ __forceinline__ void target_meta(const float* __restrict__ bbox_tgt,
                                            int tid, bool& valid, int& gi, int& gj,
                                            float& fx, float& fy, float& w, float& h,
                                            int& best_a) {
    const int b = tid >> 3, t = tid & 7;
    const float* tg = bbox_tgt + (size_t)(b * Tc + t) * 4;
    float x = tg[0], y = tg[1];
    w = tg[2]; h = tg[3];
    valid = ((x + y + w + h) != 0.0f);
    float gx = x * (float)Gc, gy = y * (float)Gc;
    gi = (int)floorf(gx); gj = (int)floorf(gy);
    gi = min(max(gi, 0), Gc - 1); gj = min(max(gj, 0), Gc - 1);
    fx = gx - floorf(gx); fy = gy - floorf(gy);

    // anchor IoU argmax (first-max tie-break via strict >)
    float x1a = fx - w * 0.5f, x2a = fx + w * 0.5f;
    float y1a = fy - h * 0.5f, y2a = fy + h * 0.5f;
    float a1 = (x2a - x1a + 1.0f) * (y2a - y1a + 1.0f);
    const float adim[Ac] = {0.24f, 0.12f, 0.08f, 0.28f, 0.15f};
    best_a = 0;
    float best_iou = -1e30f;
    for (int a = 0; a < Ac; ++a) {
        float x1b = 0.5f - adim[a] * 0.5f, x2b = 0.5f + adim[a] * 0.5f;
        float iw = fminf(x2a, x2b) - fmaxf(x1a, x1b) + 1.0f;
        float ih = fminf(y2a, x2b) - fmaxf(y1a, x1b) + 1.0f;  // square anchors: y-bounds == x-bounds
        float inter = iw * ih;
        float a2 = (x2b - x1b + 1.0f) * (x2b - x1b + 1.0f);
        float iou = inter / (a1 + a2 - inter + 1e-16f);
        if (iou > best_iou) { best_iou = iou; best_a = a; }
    }
}

// ---------------------------------------------------------------------------
// K1: blocks 0..CONF_BLOCKS-1 -> conf^2 partials (float4).  block CONF_BLOCKS
//     -> per-target meta (lin, winner) into ws.
// ---------------------------------------------------------------------------
__global__ __launch_bounds__(NT) void k1_conf_meta(
        const float* __restrict__ bbox_pred,
        const float* __restrict__ bbox_tgt,
        float* __restrict__ ws_f, int* __restrict__ ws_i) {
    if (blockIdx.x < CONF_BLOCKS) {
        __shared__ float red[NT];
        const float4* p4 = (const float4*)bbox_pred;
        float acc = 0.0f;
        for (int j = blockIdx.x * NT + threadIdx.x; j < NF4;
             j += CONF_BLOCKS * NT) {
            float4 f = p4[j];
            int r = (4 * j) % 5;   // position of f.x within its 5-group
            float v = (r == 4) ? f.x : (r == 3) ? f.y : (r == 2) ? f.z
                    : (r == 1) ? f.w : 0.0f;
            acc += v * v;
        }
        red[threadIdx.x] = acc;
        __syncthreads();
        for (int s = NT / 2; s > 0; s >>= 1) {
            if (threadIdx.x < s) red[threadIdx.x] += red[threadIdx.x + s];
            __syncthreads();
        }
        if (threadIdx.x == 0) ws_f[blockIdx.x] = red[0];
    } else {
        // meta block
        __shared__ int s_lin[NT];
        const int tid = threadIdx.x;
        const int b = tid >> 3, t = tid & 7;
        bool valid; int gi, gj, best_a; float fx, fy, w, h;
        target_meta(bbox_tgt, tid, valid, gi, gj, fx, fy, w, h, best_a);
        int lin = valid ? (((b * Gc + gj) * Gc + gi) * Ac + best_a) : NCELLS;
        s_lin[tid] = lin;
        __syncthreads();
        bool winner = valid;
        if (valid) {
            for (int t2 = t + 1; t2 < Tc; ++t2)
                if (s_lin[(b << 3) + t2] == lin) { winner = false; break; }
        }
        ws_i[256 + tid] = lin;
        ws_i[512 + tid] = winner ? 1 : 0;
    }
}

// ---------------------------------------------------------------------------
// K2: one wave per target -> landmark L2 distance (0 if not winner)
// ---------------------------------------------------------------------------
__global__ __launch_bounds__(64) void k2_lmdist(
        const float* __restrict__ lm_pred,
        const float* __restrict__ lm_tgt,
        const int* __restrict__ ws_i,
        float* __restrict__ ws_f) {
    const int tgt = blockIdx.x;          // 0..255
    const int lane = threadIdx.x;        // 0..63
    int winner = ws_i[512 + tgt];
    int lin = ws_i[256 + tgt];
    float acc = 0.0f;
    if (winner && lane < 34) {
        const float4* lp = (const float4*)(lm_pred + (size_t)lin * 136);
        const float4* lt = (const float4*)(lm_tgt + (size_t)tgt * 136);
        float4 a = lp[lane], b = lt[lane];
        float dx = a.x - b.x, dy = a.y - b.y, dz = a.z - b.z, dw = a.w - b.w;
        acc = dx * dx + dy * dy + dz * dz + dw * dw;
    }
    // wave reduction over 64 lanes
    for (int off = 32; off > 0; off >>= 1)
        acc += __shfl_down(acc, off, 64);
    if (lane == 0) ws_f[1024 + tgt] = winner ? sqrtf(acc) : 0.0f;
}

// ---------------------------------------------------------------------------
// K3: final combine (1 block, 256 threads = one thread per target)
// ---------------------------------------------------------------------------
__device__ __forceinline__ float block_sum(float v, float* red, int tid) {
    red[tid] = v;
    __syncthreads();
    for (int s = NT / 2; s > 0; s >>= 1) {
        if (tid < s) red[tid] += red[tid + s];
        __syncthreads();
    }
    float r = red[0];
    __syncthreads();
    return r;
}

__global__ __launch_bounds__(NT) void k3_final(
        const float* __restrict__ bbox_pred,
        const float* __restrict__ bbox_tgt,
        const float* __restrict__ ws_f,
        const int* __restrict__ ws_i,
        float* __restrict__ out) {
    const int tid = threadIdx.x;
    const int b = tid >> 3, t = tid & 7;
    __shared__ float s_red[NT];
    __shared__ int s_cnt[NT];

    bool valid; int gi, gj, best_a; float fx, fy, w, h;
    target_meta(bbox_tgt, tid, valid, gi, gj, fx, fy, w, h, best_a);
    int lin = ws_i[256 + tid];
    int winner = ws_i[512 + tid];
    float dist = ws_f[1024 + tid];

    float l0 = log1pf(fx), l1 = log1pf(fy), l2 = log1pf(w), l3 = log1pf(h);

    float c_nme = 0.0f, c_sl1 = 0.0f, c_cobj = 0.0f, c_csq = 0.0f;
    if (winner) {
        const float* bp = bbox_pred + (size_t)lin * 5;
        float conf = bp[4];
        c_cobj = (conf - 1.0f) * (conf - 1.0f);
        c_csq = conf * conf;
        float lb[4] = {l0, l1, l2, l3};
        for (int k = 0; k < 4; ++k) {
            float d = bp[k] - lb[k];
            float ad = fabsf(d);
            c_sl1 += (ad < 1.0f) ? 0.5f * d * d : (ad - 0.5f);
        }
        c_nme = dist / (sqrtf(l2 * l3) * 288.0f * 68.0f);
    }

    s_cnt[tid] = winner;
    __syncthreads();
    for (int s = NT / 2; s > 0; s >>= 1) {
        if (tid < s) s_cnt[tid] += s_cnt[tid + s];
        __syncthreads();
    }
    int cnt = s_cnt[0];
    __syncthreads();
    float nobj = fmaxf((float)cnt, 1.0f);
    float n_noobj = fmaxf((float)(NCELLS - cnt), 1.0f);

    float sum_nme  = block_sum(c_nme, s_red, tid);
    float sum_sl1  = block_sum(c_sl1, s_red, tid);
    float sum_cobj = block_sum(c_cobj, s_red, tid);
    float sum_csq  = block_sum(c_csq, s_red, tid);
    float s_total  = block_sum(tid < CONF_BLOCKS ? ws_f[tid] : 0.0f, s_red, tid);

    if (tid == 0) {
        out[0] = sum_nme / nobj;
        out[1] = 5.0f * sum_sl1 / (nobj * 4.0f);
        out[2] = 0.5f * (s_total - sum_csq) / n_noobj + sum_cobj / nobj;
    }

    // best_pred per target
    const float* cp = bbox_pred + (size_t)((b * Gc + gj) * Gc + gi) * Ac * 5;
    float x1g = l0 - l2 * 0.5f, x2g = l0 + l2 * 0.5f;
    float y1g = l1 - l3 * 0.5f, y2g = l1 + l3 * 0.5f;
    float ag = (x2g - x1g + 1.0f) * (y2g - y1g + 1.0f);
    int bp_idx = 0;
    float bp_iou = -1e30f;
    for (int a = 0; a < Ac; ++a) {
        float cx = cp[a * 5 + 0], cy = cp[a * 5 + 1];
        float pw = cp[a * 5 + 2], ph = cp[a * 5 + 3];
        float x1p = cx - pw * 0.5f, x2p = cx + pw * 0.5f;
        float y1p = cy - ph * 0.5f, y2p = cy + ph * 0.5f;
        float iw = fminf(x2g, x2p) - fmaxf(x1g, x1p) + 1.0f;
        float ih = fminf(y2g, y2p) - fmaxf(y1g, y1p) + 1.0f;
        float inter = iw * ih;
        float ap = (x2p - x1p + 1.0f) * (y2p - y1p + 1.0f);
        float iou = inter / (ag + ap - inter + 1e-16f);
        if (iou > bp_iou) { bp_iou = iou; bp_idx = a; }
    }
    float bx = cp[bp_idx * 5 + 0], by = cp[bp_idx * 5 + 1];
    float bw = cp[bp_idx * 5 + 2], bh = cp[bp_idx * 5 + 3];
    float bconf = cp[bp_idx * 5 + 4];
    float* op = out + 3 + (size_t)tid * 5;
    if (valid) {
        op[0] = bx - bw * 0.5f; op[1] = bx + bw * 0.5f;
        op[2] = by - bh * 0.5f; op[3] = by + bh * 0.5f; op[4] = bconf;
    } else {
        op[0] = 0.0f; op[1] = 0.0f; op[2] = 0.0f; op[3] = 0.0f; op[4] = 0.0f;
    }
}

extern "C" void kernel_launch(void* const* d_in, const int* in_sizes, int n_in,
                              void* d_out, int out_size, void* d_ws, size_t ws_size,
                              hipStream_t stream) {
    const float* bbox_pred = (const float*)d_in[0];
    const float* lm_pred   = (const float*)d_in[1];
    const float* bbox_tgt  = (const float*)d_in[2];
    const float* lm_tgt    = (const float*)d_in[3];
    float* out = (float*)d_out;
    float* ws_f = (float*)d_ws;
    int* ws_i = (int*)d_ws;

    k1_conf_meta<<<CONF_BLOCKS + 1, NT, 0, stream>>>(bbox_pred, bbox_tgt, ws_f, ws_i);
    k2_lmdist<<<256, 64, 0, stream>>>(lm_pred, lm_tgt, ws_i, ws_f);
    k3_final<<<1, NT, 0, stream>>>(bbox_pred, bbox_tgt, ws_f, ws_i, out);
}